// Round 8
// baseline (107.689 us; speedup 1.0000x reference)
//
#include <hip/hip_runtime.h>
#include <math.h>

// NormalLoss: for each template vertex (M=6890), take the K=15 scan points
// (N=20000) with LARGEST distance, among them pick the min-angle normal
// match, loss = mean ||sv[sel]-tv||.
//
// Round-8 design (r7's batch-sort drains regressed vs r6's per-event
// inserts -> revert to r6 main and trim):
//  * bootstrap over FIRST 128 sorted points: two independent sort64 chains
//    (ILP) + one bitonic merge64 (r7-proven) -> initial thr at the 88.7th
//    percentile of the hot region, ~halving downstream insert events.
//  * reduce folded into main via last-block ticket (device-scope atomics;
//    no co-residency assumption) -> one fewer graph node.
//  * hist -> scan_scatter -> main pipeline otherwise as r6 (absmax 0.0 x6):
//    bucket-sort by |p|^2 desc, bucket-edge suffix bound, early break when
//    (bound+|tv|)^2 < 15th-largest d^2, ballot/popcount sorted inserts with
//    immediate thr tightening. All tie-breaks explicit on (d2, origIdx).

constexpr int K = 15;
constexpr int NBUCK = 256;
constexpr int WAVES = 4;     // waves (=vertices) per block in main kernel

__device__ __forceinline__ int bucket_of(float k2) {
    int b = (int)(k2 * 8.0f);           // 0.125-wide buckets over |p|^2 in [0,32)
    b = b > (NBUCK - 1) ? (NBUCK - 1) : b;
    return (NBUCK - 1) - b;             // bucket 0 = largest |p|
}

__global__ __launch_bounds__(256) void hist_kernel(
    const float* __restrict__ sv, int* __restrict__ blkhist,
    unsigned* __restrict__ ticket, int N)
{
    __shared__ int h[NBUCK];
    int t = threadIdx.x;
    h[t] = 0;
    if (blockIdx.x == 0 && t == 0)
        __hip_atomic_store(ticket, 0u, __ATOMIC_RELAXED, __HIP_MEMORY_SCOPE_AGENT);
    __syncthreads();
    int i = blockIdx.x * 256 + t;
    if (i < N) {
        float x = sv[3*i], y = sv[3*i+1], z = sv[3*i+2];
        atomicAdd(&h[bucket_of(fmaf(x, x, fmaf(y, y, z*z)))], 1);
    }
    __syncthreads();
    blkhist[blockIdx.x * NBUCK + t] = h[t];   // full-row overwrite (poison-safe)
}

__global__ __launch_bounds__(256) void scan_scatter_kernel(
    const float* __restrict__ sv,
    const int*   __restrict__ blkhist,  // [nblk][NBUCK]
    float4*      __restrict__ sorted,   // [N] out: (x,y,z,bitcast(origIdx))
    float*       __restrict__ smax,     // [nb] out: |p| upper bound at pos >= j*64
    int N, int nb, int nblk)
{
    __shared__ int tmp[NBUCK];
    __shared__ int startSh[NBUCK];
    __shared__ int cursor[NBUCK];
    const int t   = threadIdx.x;
    const int blk = blockIdx.x;

    int mine = 0, total = 0;
#pragma unroll 8
    for (int b = 0; b < nblk; ++b) {
        int v = blkhist[b * NBUCK + t];
        if (b < blk) mine += v;
        total += v;
    }
    tmp[t] = total;
    __syncthreads();
    for (int d = 1; d < NBUCK; d <<= 1) {
        int u = (t >= d) ? tmp[t - d] : 0;
        __syncthreads();
        tmp[t] += u;
        __syncthreads();
    }
    int startv = tmp[t] - total;        // exclusive bucket start
    startSh[t] = startv;
    cursor[t]  = startv + mine;         // this block's write base per bucket
    __syncthreads();

    if (blk == 0) {
        // smax[j]: bucket-edge upper bound on |p| for positions >= j*64;
        // exact and independent of within-bucket order.
        for (int j = t; j < nb; j += 256) {
            int pos = j * 64;
            int lo = 0, hi = NBUCK - 1;
            while (lo < hi) {
                int mid = (lo + hi + 1) >> 1;
                if (startSh[mid] <= pos) lo = mid; else hi = mid - 1;
            }
            int bOrig = (NBUCK - 1) - lo;
            smax[j] = sqrtf((float)(bOrig + 1) * 0.125f);
        }
    }

    int i = blk * 256 + t;
    if (i < N) {
        float x = sv[3*i], y = sv[3*i+1], z = sv[3*i+2];
        float k2 = fmaf(x, x, fmaf(y, y, z*z));
        int pos = atomicAdd(&cursor[bucket_of(k2)], 1);   // LDS atomic
        sorted[pos] = make_float4(x, y, z, __int_as_float(i));
    }
}

// 64-lane bitonic sort, descending by (v desc, idx asc) — strict total order
__device__ __forceinline__ void sort64(float& v, int& idx, int lane) {
#pragma unroll
    for (int k = 2; k <= 64; k <<= 1) {
#pragma unroll
        for (int j = k >> 1; j > 0; j >>= 1) {
            float ov = __shfl_xor(v, j);
            int   oi = __shfl_xor(idx, j);
            bool up    = ((lane & k) == 0);
            bool lower = ((lane & j) == 0);
            bool mine  = (v > ov) || (v == ov && idx < oi);
            bool keep  = lower ? (up ? mine : !mine) : (up ? !mine : mine);
            if (!keep) { v = ov; idx = oi; }
        }
    }
}

// merge sorted-desc B into sorted-desc A; A keeps the top-64 (sorted desc)
__device__ __forceinline__ void merge64(float& av, int& ai, float bv, int bi,
                                        int lane) {
    bv = __shfl(bv, 63 - lane);          // reverse B -> A·B' bitonic
    bi = __shfl(bi, 63 - lane);
    {
        bool aB = (av > bv) || (av == bv && ai < bi);
        av = aB ? av : bv;
        ai = aB ? ai : bi;
    }
#pragma unroll
    for (int j = 32; j > 0; j >>= 1) {   // clean top half, descending
        float ov = __shfl_xor(av, j);
        int   oi = __shfl_xor(ai, j);
        bool lower = ((lane & j) == 0);
        bool mine  = (av > ov) || (av == ov && ai < oi);
        bool keep  = lower ? mine : !mine;
        if (!keep) { av = ov; ai = oi; }
    }
}

template<bool SORTED>
__global__ __launch_bounds__(WAVES * 64) void knn_loss_kernel(
    const float4* __restrict__ pts,   // sorted points (SORTED only)
    const float*  __restrict__ smax,  // suffix |p| upper bound per 64-block
    const float*  __restrict__ sv,    // [N,3] original scan vertices
    const float*  __restrict__ tv,    // [M,3]
    const float*  __restrict__ sn,    // [N,3]
    const float*  __restrict__ tn,    // [M,3]
    float*    __restrict__ partial,   // [gridDim.x]
    unsigned* __restrict__ ticket,    // zeroed by hist_kernel
    float*    __restrict__ out,
    int N, int M, float invM)
{
    __shared__ float bsum[WAVES];
    __shared__ bool  isLast;
    const int lane = threadIdx.x & 63;
    const int w    = threadIdx.x >> 6;
    const int m    = blockIdx.x * WAVES + w;   // wave-uniform
    const bool valid = (m < M);                // wave-uniform branch

    float contrib = 0.0f;
    if (valid) {
        const float tvx = tv[3*m], tvy = tv[3*m+1], tvz = tv[3*m+2];
        const float tlen = sqrtf(tvx*tvx + tvy*tvy + tvz*tvz);

        // ---- bootstrap: exact sorted top-64 of the first 128 points ----
        float av; int ai;      // chain A: block 0
        float bv; int bi;      // chain B: block 1 (independent -> ILP)
        {
            int l0 = (lane < N) ? lane : 0;
            int l1 = (64 + lane < N) ? (64 + lane) : 0;
            float p0x, p0y, p0z, p1x, p1y, p1z;
            if (SORTED) {
                float4 q0 = pts[l0], q1 = pts[l1];
                p0x = q0.x; p0y = q0.y; p0z = q0.z; ai = __float_as_int(q0.w);
                p1x = q1.x; p1y = q1.y; p1z = q1.z; bi = __float_as_int(q1.w);
            } else {
                p0x = sv[3*l0]; p0y = sv[3*l0+1]; p0z = sv[3*l0+2]; ai = l0;
                p1x = sv[3*l1]; p1y = sv[3*l1+1]; p1z = sv[3*l1+2]; bi = l1;
            }
            float dx = p0x - tvx, dy = p0y - tvy, dz = p0z - tvz;
            av = fmaf(dx, dx, fmaf(dy, dy, dz * dz));
            dx = p1x - tvx; dy = p1y - tvy; dz = p1z - tvz;
            bv = fmaf(dx, dx, fmaf(dy, dy, dz * dz));
            if (lane >= N)      { av = -1.0f; ai = 0x7FFFFFFF; }
            if (64 + lane >= N) { bv = -1.0f; bi = 0x7FFFFFFF; }
        }
        sort64(av, ai, lane);
        sort64(bv, bi, lane);
        merge64(av, ai, bv, bi, lane);
        // lanes hold sorted-desc top-64 of first 128; top-K in lanes 0..14
        float eV = (lane < K) ? av : -1.0f;
        int   eI = ai;
        float thr = __shfl(av, K - 1);   // 15th-largest d2 so far

        // ---- main scan (r6-proven insert machinery) ----
        for (int ib = 128; ib < N; ib += 64) {
            int  i   = ib + lane;
            bool has = (i < N);
            float d2; int oi2;
            if (SORTED) {
                float4 q = pts[has ? i : 0];           // load first (overlaps smax)
                float bnd = smax[ib >> 6] + tlen;      // d <= |p| + |tv|
                if (bnd * bnd * 1.00001f < thr) break; // margin covers rounding
                float dx = q.x - tvx, dy = q.y - tvy, dz = q.z - tvz;
                d2 = fmaf(dx, dx, fmaf(dy, dy, dz * dz));
                oi2 = __float_as_int(q.w);
            } else {
                int g = has ? i : 0;
                float dx = sv[3*g] - tvx, dy = sv[3*g+1] - tvy, dz = sv[3*g+2] - tvz;
                d2 = fmaf(dx, dx, fmaf(dy, dy, dz * dz));
                oi2 = i;
            }
            // >= : an equal-d2 candidate with lower original idx must displace
            unsigned long long mb = __ballot(has && (d2 >= thr));
            while (mb) {
                int src = __ffsll(mb) - 1;
                mb &= mb - 1;
                float cv = __shfl(d2, src);
                int   ci = __shfl(oi2, src);
                unsigned long long bb =
                    __ballot((eV > cv) || (eV == cv && eI < ci)) & 0x7FFFull;
                int p = __popcll(bb);
                if (p < K) {   // wave-uniform
                    float uv = __shfl_up(eV, 1);
                    int   ui = __shfl_up(eI, 1);
                    if (lane < K) {
                        if (lane == p)      { eV = cv; eI = ci; }
                        else if (lane > p)  { eV = uv; eI = ui; }
                    }
                    thr = __shfl(eV, K - 1);       // tighten + prune doomed
                    if (mb) mb &= __ballot(d2 >= thr);
                }
            }
        }

        // ---- epilogue: argmin angle over top-K, tie-break by rank (= lane) ----
        const float tnx = tn[3*m], tny = tn[3*m+1], tnz = tn[3*m+2];
        float ang = 3.0e38f;
        int myI = eI;
        if (lane < K && myI != 0x7FFFFFFF) {
            float dot = sn[3*myI]*tnx + sn[3*myI+1]*tny + sn[3*myI+2]*tnz;
            dot = fminf(1.0f, fmaxf(-1.0f, dot));
            ang = acosf(dot) * 57.29577951308232f;   // degrees, matches jnp
        }
        float ba = ang; int br = lane; int bi2 = myI;
#pragma unroll
        for (int s = 1; s < 16; s <<= 1) {
            float oa  = __shfl_xor(ba, s);
            int   orr = __shfl_xor(br, s);
            int   oi  = __shfl_xor(bi2, s);
            bool take = (oa < ba) || (oa == ba && orr < br);
            if (take) { ba = oa; br = orr; bi2 = oi; }
        }
        if (lane == 0) {
            float dx = sv[3*bi2]   - tvx;
            float dy = sv[3*bi2+1] - tvy;
            float dz = sv[3*bi2+2] - tvz;
            contrib = sqrtf(dx*dx + dy*dy + dz*dz) * invM;
        }
    }

    if (lane == 0) bsum[w] = contrib;
    __syncthreads();
    if (threadIdx.x == 0) {
        float s = bsum[0] + bsum[1] + bsum[2] + bsum[3];
        __hip_atomic_store(&partial[blockIdx.x], s,
                           __ATOMIC_RELAXED, __HIP_MEMORY_SCOPE_AGENT);
        unsigned t = __hip_atomic_fetch_add(ticket, 1u, __ATOMIC_ACQ_REL,
                                            __HIP_MEMORY_SCOPE_AGENT);
        isLast = (t == gridDim.x - 1);   // last block: all partials visible
    }
    __syncthreads();
    if (isLast) {
        float s = 0.0f;
        for (int i = threadIdx.x; i < gridDim.x; i += WAVES * 64)
            s += __hip_atomic_load(&partial[i], __ATOMIC_RELAXED,
                                   __HIP_MEMORY_SCOPE_AGENT);
#pragma unroll
        for (int d = 1; d < 64; d <<= 1) s += __shfl_xor(s, d);
        if (lane == 0) bsum[w] = s;
        __syncthreads();
        if (threadIdx.x == 0)
            out[0] = bsum[0] + bsum[1] + bsum[2] + bsum[3];
    }
}

extern "C" void kernel_launch(void* const* d_in, const int* in_sizes, int n_in,
                              void* d_out, int out_size, void* d_ws, size_t ws_size,
                              hipStream_t stream) {
    const float* sv = (const float*)d_in[0];   // scan_vertices   [1,N,3]
    const float* tv = (const float*)d_in[1];   // template_vertices [1,M,3]
    const float* sn = (const float*)d_in[2];   // scan_normals    [N,3]
    const float* tn = (const float*)d_in[3];   // template_normals [M,3]
    // d_in[4] = K_knn (fixed 15, compile-time)

    int N = in_sizes[0] / 3;
    int M = in_sizes[1] / 3;
    int nb = (N + 63) / 64;
    float* out = (float*)d_out;
    float invM = 1.0f / (float)M;
    int grid  = (M + WAVES - 1) / WAVES;
    int nblk  = (N + 255) / 256;

    // d_ws: [sorted float4 x N][smax x nb][blkhist x nblk*256][partial x grid][ticket]
    size_t offSorted  = 0;
    size_t offSmax    = offSorted + (size_t)N * sizeof(float4);
    size_t offHist    = (offSmax + (size_t)nb * sizeof(float) + 15) & ~(size_t)15;
    size_t offPartial = offHist + (size_t)nblk * NBUCK * sizeof(int);
    size_t offTicket  = offPartial + (size_t)grid * sizeof(float);
    size_t need       = offTicket + sizeof(unsigned);

    if (ws_size >= need) {
        float4*   sorted  = (float4*)  ((char*)d_ws + offSorted);
        float*    smax    = (float*)   ((char*)d_ws + offSmax);
        int*      blkhist = (int*)     ((char*)d_ws + offHist);
        float*    partial = (float*)   ((char*)d_ws + offPartial);
        unsigned* ticket  = (unsigned*)((char*)d_ws + offTicket);

        hist_kernel        <<<nblk, 256, 0, stream>>>(sv, blkhist, ticket, N);
        scan_scatter_kernel<<<nblk, 256, 0, stream>>>(sv, blkhist, sorted,
                                                      smax, N, nb, nblk);
        knn_loss_kernel<true><<<grid, WAVES * 64, 0, stream>>>(
            sorted, smax, sv, tv, sn, tn, partial, ticket, out, N, M, invM);
    } else {
        // minimal fallback: needs only partial+ticket
        float*    partial = (float*)d_ws;
        unsigned* ticket  = (unsigned*)((char*)d_ws + (size_t)grid * sizeof(float));
        hist_kernel<<<1, 256, 0, stream>>>(sv, (int*)d_ws, ticket, 0); // zero ticket only
        knn_loss_kernel<false><<<grid, WAVES * 64, 0, stream>>>(
            nullptr, nullptr, sv, tv, sn, tn, partial, ticket, out, N, M, invM);
    }
}

// Round 9
// 87.886 us; speedup vs baseline: 1.2253x; 1.2253x over previous
//
#include <hip/hip_runtime.h>
#include <math.h>

// NormalLoss: for each template vertex (M=6890), take the K=15 scan points
// (N=20000) with LARGEST distance, among them pick the min-angle normal
// match, loss = mean ||sv[sel]-tv||.
//
// Round-9 design (r8 regressed: bigger bootstrap +25% shuffle ops and an
// acq_rel same-address ticket; r8 counters showed main=41us, occ=39% ->
// scheduling tail from 4-wave blocks):
//  * main kernel: ONE WAVE PER BLOCK (64 threads, grid=M). No syncthreads,
//    no shared bsum, 1-wave scheduling granularity kills the tail where
//    finished waves idled behind 3 sibling waves in a 256-thread block.
//  * main structure = r6's proven machinery (absmax 0.0): single sort64
//    bootstrap over the 64 largest-|p| points, ballot/popcount sorted
//    inserts with immediate thr tightening, early break when
//    (suffixBound|p| + |tv|)^2 < 15th-largest d^2.
//  * hist -> scan_scatter -> main -> reduce (separate node, proven r6).
//    All tie-breaks explicit on (d2, origIdx) -> exact jax semantics.

constexpr int K = 15;
constexpr int NBUCK = 256;

__device__ __forceinline__ int bucket_of(float k2) {
    int b = (int)(k2 * 8.0f);           // 0.125-wide buckets over |p|^2 in [0,32)
    b = b > (NBUCK - 1) ? (NBUCK - 1) : b;
    return (NBUCK - 1) - b;             // bucket 0 = largest |p|
}

__global__ __launch_bounds__(256) void hist_kernel(
    const float* __restrict__ sv, int* __restrict__ blkhist, int N)
{
    __shared__ int h[NBUCK];
    int t = threadIdx.x;
    h[t] = 0;
    __syncthreads();
    int i = blockIdx.x * 256 + t;
    if (i < N) {
        float x = sv[3*i], y = sv[3*i+1], z = sv[3*i+2];
        atomicAdd(&h[bucket_of(fmaf(x, x, fmaf(y, y, z*z)))], 1);
    }
    __syncthreads();
    blkhist[blockIdx.x * NBUCK + t] = h[t];   // full-row overwrite (poison-safe)
}

__global__ __launch_bounds__(256) void scan_scatter_kernel(
    const float* __restrict__ sv,
    const int*   __restrict__ blkhist,  // [nblk][NBUCK]
    float4*      __restrict__ sorted,   // [N] out: (x,y,z,bitcast(origIdx))
    float*       __restrict__ smax,     // [nb] out: |p| upper bound at pos >= j*64
    int N, int nb, int nblk)
{
    __shared__ int tmp[NBUCK];
    __shared__ int startSh[NBUCK];
    __shared__ int cursor[NBUCK];
    const int t   = threadIdx.x;
    const int blk = blockIdx.x;

    int mine = 0, total = 0;
#pragma unroll 8
    for (int b = 0; b < nblk; ++b) {
        int v = blkhist[b * NBUCK + t];
        if (b < blk) mine += v;
        total += v;
    }
    tmp[t] = total;
    __syncthreads();
    for (int d = 1; d < NBUCK; d <<= 1) {
        int u = (t >= d) ? tmp[t - d] : 0;
        __syncthreads();
        tmp[t] += u;
        __syncthreads();
    }
    int startv = tmp[t] - total;        // exclusive bucket start
    startSh[t] = startv;
    cursor[t]  = startv + mine;         // this block's write base per bucket
    __syncthreads();

    if (blk == 0) {
        // smax[j]: bucket-edge upper bound on |p| for positions >= j*64;
        // exact and independent of within-bucket order.
        for (int j = t; j < nb; j += 256) {
            int pos = j * 64;
            int lo = 0, hi = NBUCK - 1;
            while (lo < hi) {
                int mid = (lo + hi + 1) >> 1;
                if (startSh[mid] <= pos) lo = mid; else hi = mid - 1;
            }
            int bOrig = (NBUCK - 1) - lo;
            smax[j] = sqrtf((float)(bOrig + 1) * 0.125f);
        }
    }

    int i = blk * 256 + t;
    if (i < N) {
        float x = sv[3*i], y = sv[3*i+1], z = sv[3*i+2];
        float k2 = fmaf(x, x, fmaf(y, y, z*z));
        int pos = atomicAdd(&cursor[bucket_of(k2)], 1);   // LDS atomic
        sorted[pos] = make_float4(x, y, z, __int_as_float(i));
    }
}

// 64-lane bitonic sort, descending by (v desc, idx asc) — strict total order
__device__ __forceinline__ void sort64(float& v, int& idx, int lane) {
#pragma unroll
    for (int k = 2; k <= 64; k <<= 1) {
#pragma unroll
        for (int j = k >> 1; j > 0; j >>= 1) {
            float ov = __shfl_xor(v, j);
            int   oi = __shfl_xor(idx, j);
            bool up    = ((lane & k) == 0);
            bool lower = ((lane & j) == 0);
            bool mine  = (v > ov) || (v == ov && idx < oi);
            bool keep  = lower ? (up ? mine : !mine) : (up ? !mine : mine);
            if (!keep) { v = ov; idx = oi; }
        }
    }
}

template<bool SORTED>
__global__ __launch_bounds__(64) void knn_loss_kernel(
    const float4* __restrict__ pts,   // sorted points (SORTED only)
    const float*  __restrict__ smax,  // suffix |p| upper bound per 64-block
    const float*  __restrict__ sv,    // [N,3] original scan vertices
    const float*  __restrict__ tv,    // [M,3]
    const float*  __restrict__ sn,    // [N,3]
    const float*  __restrict__ tn,    // [M,3]
    float* __restrict__ partial,      // [M] per-vertex contributions
    int N, float invM)
{
    const int lane = threadIdx.x;     // 0..63, one wave per block
    const int m    = blockIdx.x;      // grid.x == M exactly

    const float tvx = tv[3*m], tvy = tv[3*m+1], tvz = tv[3*m+2];
    const float tlen = sqrtf(tvx*tvx + tvy*tvy + tvz*tvz);

    // ---- bootstrap: bitonic-sort first 64 points desc by (d2, -idx) ----
    float v; int idx;
    {
        int l = (lane < N) ? lane : 0;
        float px, py, pz;
        if (SORTED) {
            float4 q = pts[l];
            px = q.x; py = q.y; pz = q.z; idx = __float_as_int(q.w);
        } else {
            px = sv[3*l]; py = sv[3*l+1]; pz = sv[3*l+2]; idx = l;
        }
        float dx = px - tvx, dy = py - tvy, dz = pz - tvz;
        v = fmaf(dx, dx, fmaf(dy, dy, dz * dz));
        if (lane >= N) { v = -1.0f; idx = 0x7FFFFFFF; }
    }
    sort64(v, idx, lane);
    // lanes 0..K-1 hold the exact top-K of the first 64 (sorted desc)
    float eV = (lane < K) ? v : -1.0f;
    int   eI = idx;
    float thr = __shfl(v, K - 1);   // current 15th-largest d2

    // ---- main scan (r6-proven insert machinery) ----
    for (int ib = 64; ib < N; ib += 64) {
        int  i   = ib + lane;
        bool has = (i < N);
        float d2; int oi2;
        if (SORTED) {
            float4 q = pts[has ? i : 0];           // load first (overlaps smax)
            float bnd = smax[ib >> 6] + tlen;      // d <= |p| + |tv|
            if (bnd * bnd * 1.00001f < thr) break; // margin covers rounding
            float dx = q.x - tvx, dy = q.y - tvy, dz = q.z - tvz;
            d2 = fmaf(dx, dx, fmaf(dy, dy, dz * dz));
            oi2 = __float_as_int(q.w);
        } else {
            int g = has ? i : 0;
            float dx = sv[3*g] - tvx, dy = sv[3*g+1] - tvy, dz = sv[3*g+2] - tvz;
            d2 = fmaf(dx, dx, fmaf(dy, dy, dz * dz));
            oi2 = i;
        }
        // >= : an equal-d2 candidate with lower original idx must displace
        unsigned long long mb = __ballot(has && (d2 >= thr));
        while (mb) {
            int src = __ffsll(mb) - 1;
            mb &= mb - 1;
            float cv = __shfl(d2, src);
            int   ci = __shfl(oi2, src);
            unsigned long long bb =
                __ballot((eV > cv) || (eV == cv && eI < ci)) & 0x7FFFull;
            int p = __popcll(bb);
            if (p < K) {   // wave-uniform
                float uv = __shfl_up(eV, 1);
                int   ui = __shfl_up(eI, 1);
                if (lane < K) {
                    if (lane == p)      { eV = cv; eI = ci; }
                    else if (lane > p)  { eV = uv; eI = ui; }
                }
                thr = __shfl(eV, K - 1);       // tighten + prune doomed
                if (mb) mb &= __ballot(d2 >= thr);
            }
        }
    }

    // ---- epilogue: argmin angle over top-K, tie-break by rank (= lane) ----
    const float tnx = tn[3*m], tny = tn[3*m+1], tnz = tn[3*m+2];
    float ang = 3.0e38f;
    int myI = eI;
    if (lane < K && myI != 0x7FFFFFFF) {
        float dot = sn[3*myI]*tnx + sn[3*myI+1]*tny + sn[3*myI+2]*tnz;
        dot = fminf(1.0f, fmaxf(-1.0f, dot));
        ang = acosf(dot) * 57.29577951308232f;   // degrees, matches jnp
    }
    float ba = ang; int br = lane; int bi = myI;
#pragma unroll
    for (int s = 1; s < 16; s <<= 1) {
        float oa  = __shfl_xor(ba, s);
        int   orr = __shfl_xor(br, s);
        int   oi  = __shfl_xor(bi, s);
        bool take = (oa < ba) || (oa == ba && orr < br);
        if (take) { ba = oa; br = orr; bi = oi; }
    }
    if (lane == 0) {
        float dx = sv[3*bi]   - tvx;
        float dy = sv[3*bi+1] - tvy;
        float dz = sv[3*bi+2] - tvz;
        partial[m] = sqrtf(dx*dx + dy*dy + dz*dz) * invM;
    }
}

__global__ __launch_bounds__(256) void reduce_kernel(
    const float* __restrict__ partial, float* __restrict__ out, int n)
{
    __shared__ float sh[4];
    const int lane = threadIdx.x & 63;
    const int w    = threadIdx.x >> 6;
    float s = 0.0f;
    for (int i = threadIdx.x; i < n; i += 256) s += partial[i];
#pragma unroll
    for (int d = 1; d < 64; d <<= 1) s += __shfl_xor(s, d);
    if (lane == 0) sh[w] = s;
    __syncthreads();
    if (threadIdx.x == 0) out[0] = sh[0] + sh[1] + sh[2] + sh[3];
}

extern "C" void kernel_launch(void* const* d_in, const int* in_sizes, int n_in,
                              void* d_out, int out_size, void* d_ws, size_t ws_size,
                              hipStream_t stream) {
    const float* sv = (const float*)d_in[0];   // scan_vertices   [1,N,3]
    const float* tv = (const float*)d_in[1];   // template_vertices [1,M,3]
    const float* sn = (const float*)d_in[2];   // scan_normals    [N,3]
    const float* tn = (const float*)d_in[3];   // template_normals [M,3]
    // d_in[4] = K_knn (fixed 15, compile-time)

    int N = in_sizes[0] / 3;
    int M = in_sizes[1] / 3;
    int nb = (N + 63) / 64;
    float* out = (float*)d_out;
    float invM = 1.0f / (float)M;
    int nblk  = (N + 255) / 256;

    // d_ws layout: [sorted float4 x N][smax x nb][blkhist x nblk*256][partial x M]
    size_t offSorted  = 0;
    size_t offSmax    = offSorted + (size_t)N * sizeof(float4);
    size_t offHist    = (offSmax + (size_t)nb * sizeof(float) + 15) & ~(size_t)15;
    size_t offPartial = offHist + (size_t)nblk * NBUCK * sizeof(int);
    size_t need       = offPartial + (size_t)M * sizeof(float);

    if (ws_size >= need) {
        float4* sorted  = (float4*)((char*)d_ws + offSorted);
        float*  smax    = (float*) ((char*)d_ws + offSmax);
        int*    blkhist = (int*)   ((char*)d_ws + offHist);
        float*  partial = (float*) ((char*)d_ws + offPartial);

        hist_kernel        <<<nblk, 256, 0, stream>>>(sv, blkhist, N);
        scan_scatter_kernel<<<nblk, 256, 0, stream>>>(sv, blkhist, sorted,
                                                      smax, N, nb, nblk);
        knn_loss_kernel<true><<<M, 64, 0, stream>>>(
            sorted, smax, sv, tv, sn, tn, partial, N, invM);
        reduce_kernel      <<<1, 256, 0, stream>>>(partial, out, M);
    } else {
        float* partial = (float*)d_ws;
        knn_loss_kernel<false><<<M, 64, 0, stream>>>(
            nullptr, nullptr, sv, tv, sn, tn, partial, N, invM);
        reduce_kernel      <<<1, 256, 0, stream>>>(partial, out, M);
    }
}